// Round 15
// baseline (759.333 us; speedup 1.0000x reference)
//
#include <hip/hip_runtime.h>
#include <hip/hip_bf16.h>
#include <math.h>

#define B_  256
#define T_  40
#define IN_ 2048
#define E_  512
#define H_  1024
#define V_  5000
#define G4_ 4096   // 4*H

typedef __bf16 bf16x8 __attribute__((ext_vector_type(8)));
typedef float  f32x4  __attribute__((ext_vector_type(4)));
typedef unsigned int u32x4 __attribute__((ext_vector_type(4)));
typedef unsigned short u16x8 __attribute__((ext_vector_type(8)));

__device__ __forceinline__ float sigm_f(float x) { return 1.0f / (1.0f + __expf(-x)); }
__device__ __forceinline__ float tanh_f(float x) { return 1.0f - 2.0f / (1.0f + __expf(2.0f * x)); }

__device__ __forceinline__ unsigned short f2b(float x) {
    __hip_bfloat16 h = __float2bfloat16(x);
    return *reinterpret_cast<unsigned short*>(&h);
}
__device__ __forceinline__ float b2f(unsigned short u) {
    unsigned int v = (unsigned int)u << 16;
    return __builtin_bit_cast(float, v);
}

#define GLOAD_LDS(g, l) __builtin_amdgcn_global_load_lds(                     \
    (const __attribute__((address_space(1))) unsigned int*)(g),               \
    (__attribute__((address_space(3))) unsigned int*)(l), 16, 0, 0)

// normal (L2-cached) 16B load, manual vmcnt accounting via VM_WAIT
__device__ __forceinline__ void l2_load16(u32x4* dst, const unsigned short* p) {
    asm volatile("global_load_dwordx4 %0, %1, off" : "=v"(*dst) : "v"(p));
}
// LLC-coherent (cross-XCD) stores + poll
__device__ __forceinline__ void llc_store16(unsigned short* p, u32x4 v) {
    asm volatile("global_store_dwordx4 %0, %1, off sc0 sc1" :: "v"(p), "v"(v) : "memory");
}
__device__ __forceinline__ void llc_store4(unsigned int* p, unsigned int v) {
    asm volatile("global_store_dword %0, %1, off sc0 sc1" :: "v"(p), "v"(v) : "memory");
}
// poll load: waitcnt INSIDE the asm (compiler doesn't track asm loads)
__device__ __forceinline__ unsigned int llc_load4_wait(const unsigned int* p) {
    unsigned int v;
    asm volatile("global_load_dword %0, %1, off sc0 sc1\n\ts_waitcnt vmcnt(0)"
                 : "=v"(v) : "v"(p) : "memory");
    return v;
}
#define VM_WAIT(n) do {                                                       \
    asm volatile("s_waitcnt vmcnt(" #n ")" ::: "memory");                     \
    __builtin_amdgcn_sched_barrier(0);                                        \
} while (0)

// XCD-chunked block swizzle (T1): contiguous tile range per XCD.
// Requires nwg % 8 == 0 (all call sites satisfy this).
__device__ __forceinline__ void xcd_swizzle(int& bx, int& by) {
    int gx = gridDim.x, nwg = gx * gridDim.y;
    int g0 = blockIdx.y * gx + blockIdx.x;
    int g  = (g0 & 7) * (nwg >> 3) + (g0 >> 3);
    bx = g % gx;
    by = g / gx;
}

// ---------------------------------------------------------------------------
// bf16 MFMA GEMM, depth-2 counted-vmcnt pipeline (3 LDS buffers, one raw
// barrier per K-iter).
// C = gather(A) @ Bsel^T (+ bias) (+ addMat[(row&rowMask)*addStride + col])
// aBlocked: A stored as [kblk][256 rows][16] blocks (hs layout).
// bMapQ:    B row for (permuted) col c is (c&3)*1024 + (c>>2).
// OUTMODE 0: f32 store (bias/addMat in epilogue), col guarded by N.
// OUTMODE 1: bf16 store via LDS-staged coalesced 16B writes (N%128==0;
//            addMat applied; bias ignored).
// OUTMODE 2: bf16 scalar store + bias (small matrices).
// 128x128 tile, BK=32, 256 thr = 4 waves, 16x16x32 MFMA. LDS 48 KB static.
// ---------------------------------------------------------------------------
template<int OUTMODE>
__global__ __launch_bounds__(256) void gemm_mfma(
    const unsigned short* __restrict__ A, int lda, int aBlocked,
    const int* __restrict__ gidx,
    const unsigned short* __restrict__ Bm, int ldb, int bMapQ,
    const float* __restrict__ bias,
    const float* __restrict__ addMat, int rowMask, long long addStride,
    void* __restrict__ Cout, int ldc, int N, int K)
{
    __shared__ unsigned short SH[24576];   // A bufs [3][4096] | B bufs [3][4096]

    const int tid  = threadIdx.x;
    const int wave = tid >> 6, lane = tid & 63;
    int bx, by;
    xcd_swizzle(bx, by);
    const int brow0 = by * 128, bcol0 = bx * 128;
    const int wrow0 = (wave >> 1) * 64, wcol0 = (wave & 1) * 64;

    const int srow = lane >> 2;
    const int scol = (lane & 3) * 8;
    const size_t kstep = aBlocked ? 256 : 1;
    const unsigned short *pA[2], *pB[2];
    int segoff[2];
    #pragma unroll
    for (int i = 0; i < 2; ++i) {
        int seg = wave * 2 + i;
        int row = seg * 16 + srow;
        long long ar = gidx ? (long long)gidx[brow0 + row] : (long long)(brow0 + row);
        if (aBlocked)
            pA[i] = A + ((size_t)ar << 4) + ((size_t)(scol >> 4) << 12) + (scol & 8);
        else
            pA[i] = A + (size_t)ar * lda + scol;
        int bc = bcol0 + row;
        long long wrow = bMapQ ? (long long)(((bc & 3) << 10) | (bc >> 2)) : bc;
        pB[i] = Bm + wrow * ldb + scol;
        segoff[i] = seg * 512;
    }

    f32x4 acc[4][4] = {};
    const int foff = (lane & 15) * 32 + (lane >> 4) * 8;

    #define STAGE(buf, k0)                                                    \
        GLOAD_LDS(pA[0] + (size_t)(k0) * kstep, SH + (buf) * 4096 + segoff[0]); \
        GLOAD_LDS(pA[1] + (size_t)(k0) * kstep, SH + (buf) * 4096 + segoff[1]); \
        GLOAD_LDS(pB[0] + (k0), SH + 12288 + (buf) * 4096 + segoff[0]);       \
        GLOAD_LDS(pB[1] + (k0), SH + 12288 + (buf) * 4096 + segoff[1]);

    STAGE(0, 0)
    STAGE(1, 32)

    int cur = 0;
    for (int k0 = 0; k0 < K; k0 += 32) {
        if (k0 + 32 < K) { VM_WAIT(4); } else { VM_WAIT(0); }
        __builtin_amdgcn_s_barrier();   // raw: no implicit vmcnt(0) drain

        if (k0 + 64 < K) {
            int nb = cur + 2; if (nb >= 3) nb -= 3;
            STAGE(nb, k0 + 64)
        }

        bf16x8 a[4], b[4];
        #pragma unroll
        for (int m = 0; m < 4; ++m)
            a[m] = *(const bf16x8*)&SH[cur * 4096 + (wrow0 + m * 16) * 32 + foff];
        #pragma unroll
        for (int n = 0; n < 4; ++n)
            b[n] = *(const bf16x8*)&SH[12288 + cur * 4096 + (wcol0 + n * 16) * 32 + foff];
        #pragma unroll
        for (int m = 0; m < 4; ++m)
            #pragma unroll
            for (int n = 0; n < 4; ++n)
                acc[m][n] = __builtin_amdgcn_mfma_f32_16x16x32_bf16(
                    a[m], b[n], acc[m][n], 0, 0, 0);

        ++cur; if (cur == 3) cur = 0;
    }
    #undef STAGE

    if (OUTMODE == 0) {
        #pragma unroll
        for (int m = 0; m < 4; ++m)
            #pragma unroll
            for (int j = 0; j < 4; ++j) {
                int row = brow0 + wrow0 + m * 16 + (lane >> 4) * 4 + j;
                const float* addRow = addMat
                    ? addMat + (long long)(row & rowMask) * addStride : nullptr;
                #pragma unroll
                for (int n = 0; n < 4; ++n) {
                    int col = bcol0 + wcol0 + n * 16 + (lane & 15);
                    if (col < N) {
                        float v = acc[m][n][j];
                        if (addRow) v += addRow[col];
                        if (bias)   v += bias[col];
                        ((float*)Cout)[(long long)row * ldc + col] = v;
                    }
                }
            }
    } else if (OUTMODE == 1) {
        // LDS-staged bf16 epilogue: reuse SH[0..16384) as the C tile
        __syncthreads();
        #pragma unroll
        for (int m = 0; m < 4; ++m)
            #pragma unroll
            for (int j = 0; j < 4; ++j) {
                int lr = wrow0 + m * 16 + (lane >> 4) * 4 + j;
                int row = brow0 + lr;
                const float* addRow = addMat + (long long)(row & rowMask) * addStride;
                #pragma unroll
                for (int n = 0; n < 4; ++n) {
                    int lc = wcol0 + n * 16 + (lane & 15);
                    SH[lr * 128 + lc] = f2b(acc[m][n][j] + addRow[bcol0 + lc]);
                }
            }
        __syncthreads();
        #pragma unroll
        for (int p = 0; p < 8; ++p) {
            int idx = p * 256 + tid;
            int lr = idx >> 4, lc8 = (idx & 15) * 8;
            *(u32x4*)((unsigned short*)Cout + (size_t)(brow0 + lr) * ldc +
                      bcol0 + lc8) = *(const u32x4*)&SH[lr * 128 + lc8];
        }
    } else {
        #pragma unroll
        for (int m = 0; m < 4; ++m)
            #pragma unroll
            for (int j = 0; j < 4; ++j) {
                int row = brow0 + wrow0 + m * 16 + (lane >> 4) * 4 + j;
                #pragma unroll
                for (int n = 0; n < 4; ++n) {
                    int col = bcol0 + wcol0 + n * 16 + (lane & 15);
                    if (col < N)
                        ((unsigned short*)Cout)[(long long)row * ldc + col] =
                            f2b(acc[m][n][j] + (bias ? bias[col] : 0.f));
                }
            }
    }
}

// ---------------------------------------------------------------------------
// Logits GEMM: BM=256 x BN=128 tile, K=1024. 256 thr = 4 waves (2x2), each
// wave 128x64 output (acc 8x4 frags). Depth-2 counted-vmcnt pipeline, 3 LDS
// buffers (72 KB), one raw barrier per K-iter. XCD-chunked block swizzle.
// A = hs blocked ([kblk][256 row][16]) gathered via gidx; B = Wout_bf padded.
// ---------------------------------------------------------------------------
__global__ __launch_bounds__(256, 2) void gemm_big(
    const unsigned short* __restrict__ A,
    const int* __restrict__ gidx,
    const unsigned short* __restrict__ Bm,     // [5120][1024] bf16 (padded)
    const float* __restrict__ bias,            // [5000]
    float* __restrict__ C)                     // [10240][5000] f32
{
    __shared__ unsigned short SA[3 * 8192];    // 48 KB: 3 bufs x (256x32)
    __shared__ unsigned short SB[3 * 4096];    // 24 KB: 3 bufs x (128x32)

    const int tid = threadIdx.x;
    const int wave = tid >> 6, lane = tid & 63;
    int bx, by;
    xcd_swizzle(bx, by);
    const int brow0 = by * 256, bcol0 = bx * 128;
    const int wrow0 = (wave >> 1) * 128, wcol0 = (wave & 1) * 64;

    const int srow = lane >> 2;          // 0..15
    const int scol = (lane & 3) * 8;
    const unsigned short* pA[4];
    const unsigned short* pB[2];
    int aoff[4], boff[2];
    #pragma unroll
    for (int i = 0; i < 4; ++i) {
        int seg = wave * 4 + i;          // 0..15
        int row = seg * 16 + srow;       // 0..255
        long long ar = gidx[brow0 + row];
        pA[i] = A + ((size_t)ar << 4) + ((size_t)(scol >> 4) << 12) + (scol & 8);
        aoff[i] = seg * 512;
    }
    #pragma unroll
    for (int i = 0; i < 2; ++i) {
        int seg = wave * 2 + i;          // 0..7
        int row = seg * 16 + srow;       // 0..127
        pB[i] = Bm + (size_t)(bcol0 + row) * 1024 + scol;
        boff[i] = seg * 512;
    }

    f32x4 acc[8][4] = {};
    const int foff = (lane & 15) * 32 + (lane >> 4) * 8;

    #define BSTAGE(buf, k0)                                                   \
        GLOAD_LDS(pA[0] + (size_t)(k0) * 256, SA + (buf) * 8192 + aoff[0]);   \
        GLOAD_LDS(pA[1] + (size_t)(k0) * 256, SA + (buf) * 8192 + aoff[1]);   \
        GLOAD_LDS(pA[2] + (size_t)(k0) * 256, SA + (buf) * 8192 + aoff[2]);   \
        GLOAD_LDS(pA[3] + (size_t)(k0) * 256, SA + (buf) * 8192 + aoff[3]);   \
        GLOAD_LDS(pB[0] + (k0), SB + (buf) * 4096 + boff[0]);                 \
        GLOAD_LDS(pB[1] + (k0), SB + (buf) * 4096 + boff[1]);

    BSTAGE(0, 0)
    BSTAGE(1, 32)

    int cur = 0;
    for (int k0 = 0; k0 < 1024; k0 += 32) {
        if (k0 + 32 < 1024) { VM_WAIT(6); } else { VM_WAIT(0); }
        __builtin_amdgcn_s_barrier();

        if (k0 + 64 < 1024) {
            int nb = cur + 2; if (nb >= 3) nb -= 3;
            BSTAGE(nb, k0 + 64)
        }

        bf16x8 b[4];
        #pragma unroll
        for (int n = 0; n < 4; ++n)
            b[n] = *(const bf16x8*)&SB[cur * 4096 + (wcol0 + n * 16) * 32 + foff];
        #pragma unroll
        for (int m = 0; m < 8; ++m) {
            bf16x8 a = *(const bf16x8*)&SA[cur * 8192 + (wrow0 + m * 16) * 32 + foff];
            #pragma unroll
            for (int n = 0; n < 4; ++n)
                acc[m][n] = __builtin_amdgcn_mfma_f32_16x16x32_bf16(
                    a, b[n], acc[m][n], 0, 0, 0);
        }
        ++cur; if (cur == 3) cur = 0;
    }
    #undef BSTAGE

    #pragma unroll
    for (int m = 0; m < 8; ++m)
        #pragma unroll
        for (int j = 0; j < 4; ++j) {
            int row = brow0 + wrow0 + m * 16 + (lane >> 4) * 4 + j;
            float* orow = C + (size_t)row * 5000;
            #pragma unroll
            for (int n = 0; n < 4; ++n) {
                int col = bcol0 + wcol0 + n * 16 + (lane & 15);
                if (col < V_)
                    orow[col] = acc[m][n][j] + bias[col];
            }
        }
}

// ---------------------------------------------------------------------------
// Persistent LSTM recurrence (round-12 proven protocol; NEW bid decode:
// mb = bid&3, hb = bid>>2 -> quadrant mb lives on XCDs {mb, mb+4} given the
// bid%8 round-robin, so each XCD's L2 re-reads only its own 128 KB h-slice
// per step and flag producer/consumer pairs co-locate on 2 XCDs).
// 256 WGs x 256 thr. WG (mb,hb): batch rows mb*64..+64, h-cols hb*16..+16.
// W_hh slice LDS-resident 128 KB XOR-swizzled; gates bf16 quads [T][B][1024][4]
// prefetched one step ahead; h blocked [64 kblk][256 row][16]; per-wave flag
// sc0sc1 signaling + 64-lane parallel poll.
// ---------------------------------------------------------------------------
__global__ __launch_bounds__(256) void recur_persist(
    unsigned short* __restrict__ hs,          // slots 1..40, each 262144 elems
    const unsigned short* __restrict__ Whh,   // [4096,1024] bf16
    const unsigned short* __restrict__ gates, // [T,B,1024,4] bf16 (quad)
    unsigned int* __restrict__ flags)         // [(T+1)*256], zeroed
{
    extern __shared__ unsigned short lds[];   // [64][1024] bf16 = 128 KB
    __shared__ unsigned short hstage[64][24];

    const int tid = threadIdx.x;
    const int w = tid >> 6, lane = tid & 63;
    const int mb = blockIdx.x & 3;            // quadrant -> XCD co-location
    const int hb = blockIdx.x >> 2;
    const int r16 = lane & 15, g4 = lane >> 4;
    const int sw7 = r16 & 7;
    const size_t SLOT = 262144;

    const int arow = mb * 64 + w * 16 + r16;
    const size_t abase = ((size_t)arow << 4) + ((g4 >> 1) << 12) + ((g4 & 1) << 3);
    const int orow0 = mb * 64 + w * 16 + g4 * 4;
    const int hc    = hb * 16 + r16;
    const int lrow0 = w * 16 + g4 * 4;
    const size_t gq_base = ((size_t)orow0 << 12) + ((size_t)hc << 2);

    ushort4 gqc[4], gqn[4];
    #pragma unroll
    for (int j = 0; j < 4; ++j)
        gqc[j] = *(const ushort4*)(gates + gq_base + ((size_t)j << 12));

    {
        const int q = w;
        for (int r = 0; r < 16; ++r) {
            const int g = q * 16 + r;
            const unsigned short* rowsrc =
                Whh + ((size_t)q * 1024 + hb * 16 + r) * H_;
            #pragma unroll
            for (int half = 0; half < 2; ++half) {
                int gran = (half * 64 + lane) ^ (g & 7);
                GLOAD_LDS(rowsrc + gran * 8, &lds[g * 1024 + half * 512]);
            }
        }
    }
    asm volatile("s_waitcnt vmcnt(0)" ::: "memory");
    __syncthreads();

    int qbase[4];
    #pragma unroll
    for (int q = 0; q < 4; ++q) qbase[q] = (q * 16 + r16) << 11;

    float cc[4];

    #define STORE_H(T1, HV)                                                   \
    {                                                                         \
        _Pragma("unroll")                                                     \
        for (int j = 0; j < 4; ++j) hstage[lrow0 + j][r16] = HV[j];           \
        __syncthreads();                                                      \
        if (w == 0) {                                                         \
            unsigned short* dst0 = hs + (size_t)(T1) * SLOT +                 \
                (((size_t)hb * 256 + mb * 64) << 4);                          \
            _Pragma("unroll")                                                 \
            for (int s = 0; s < 2; ++s) {                                     \
                int idx = s * 64 + lane;                                      \
                u32x4 v = *(const u32x4*)&hstage[idx >> 1][(idx & 1) * 8];    \
                llc_store16(dst0 + (size_t)idx * 8, v);                       \
            }                                                                 \
            asm volatile("s_waitcnt vmcnt(0)" ::: "memory");                  \
            if (lane == 0)                                                    \
                llc_store4(flags + ((T1) << 8) + (mb << 6) + hb, 1u);         \
        }                                                                     \
    }

    // step 0
    {
        #pragma unroll
        for (int j = 0; j < 4; ++j)
            gqn[j] = *(const ushort4*)(gates + (1ull << 20) + gq_base +
                                       ((size_t)j << 12));
        unsigned short hv[4];
        #pragma unroll
        for (int j = 0; j < 4; ++j) {
            float gi = b2f(gqc[j].x), gg = b2f(gqc[j].z), go = b2f(gqc[j].w);
            float c2 = sigm_f(gi) * tanh_f(gg);
            cc[j] = c2;
            hv[j] = f2b(sigm_f(go) * tanh_f(c2));
        }
        STORE_H(1, hv)
        #pragma unroll
        for (int j = 0; j < 4; ++j) gqc[j] = gqn[j];
    }

    for (int t = 1; t < T_; ++t) {
        {
            const unsigned int* fp = flags + ((size_t)t << 8) + (mb << 6) + lane;
            for (;;) {
                unsigned int fv = llc_load4_wait(fp);
                if (__all(fv == 1u)) break;
                __builtin_amdgcn_s_sleep(1);
            }
        }
        __builtin_amdgcn_sched_barrier(0);

        const unsigned short* hp = hs + (size_t)t * SLOT + abase;

        u32x4 a0[8], a1[8];
        #pragma unroll
        for (int u = 0; u < 8; ++u) l2_load16(&a0[u], hp + (size_t)u * 8192);
        #pragma unroll
        for (int u = 0; u < 8; ++u) l2_load16(&a1[u], hp + (size_t)(8 + u) * 8192);

        f32x4 acc[4] = {};

#define DO_CHUNK(BUF, KSB)                                                    \
        _Pragma("unroll")                                                     \
        for (int u = 0; u < 8; ++u) {                                         \
            bf16x8 a8 = __builtin_bit_cast(bf16x8, BUF[u]);                   \
            _Pragma("unroll")                                                 \
            for (int q = 0; q < 4; ++q) {                                     \
                int off = qbase[q] + (((((KSB) + u) * 4 + g4) ^ sw7) << 4);   \
                bf16x8 b8 = *(const bf16x8*)((const char*)lds + off);         \
                acc[q] = __builtin_amdgcn_mfma_f32_16x16x32_bf16(             \
                    a8, b8, acc[q], 0, 0, 0);                                 \
            }                                                                 \
        }

        VM_WAIT(8);
        DO_CHUNK(a0, 0)
        #pragma unroll
        for (int u = 0; u < 8; ++u) l2_load16(&a0[u], hp + (size_t)(16 + u) * 8192);
        VM_WAIT(8);
        DO_CHUNK(a1, 8)
        #pragma unroll
        for (int u = 0; u < 8; ++u) l2_load16(&a1[u], hp + (size_t)(24 + u) * 8192);
        VM_WAIT(8);
        DO_CHUNK(a0, 16)
        VM_WAIT(0);
        DO_CHUNK(a1, 24)
#undef DO_CHUNK

        if (t + 1 < T_) {
            #pragma unroll
            for (int j = 0; j < 4; ++j)
                gqn[j] = *(const ushort4*)(gates +
                    ((size_t)(t + 1) << 20) + gq_base + ((size_t)j << 12));
        }

        unsigned short hv[4];
        #pragma unroll
        for (int j = 0; j < 4; ++j) {
            float gi = acc[0][j] + b2f(gqc[j].x);
            float gf = acc[1][j] + b2f(gqc[j].y);
            float gg = acc[2][j] + b2f(gqc[j].z);
            float go = acc[3][j] + b2f(gqc[j].w);
            float c2 = sigm_f(gf) * cc[j] + sigm_f(gi) * tanh_f(gg);
            cc[j] = c2;
            hv[j] = f2b(sigm_f(go) * tanh_f(c2));
        }
        STORE_H(t + 1, hv)
        #pragma unroll
        for (int j = 0; j < 4; ++j) gqc[j] = gqn[j];
    }
    #undef STORE_H
}

// ---------------------------------------------------------------------------
// Fused prep: ALL bf16 conversions (incl. X and W_f) + gather indices +
// permuted bias in ONE kernel. Segments in ushort4 units:
//   [0, 640128)            emb   5001 x 512,  ld 512,  col0 0
//   [640128, 1164416)      WihE  4096 x 512,  ld 1024, col0 512
//   [1164416, 1688704)     WihA  4096 x 512,  ld 1024, col0 0
//   [1688704, 2737280)     Whh   4096 x 1024, ld 1024
//   [2737280, 4048000)     Wout  5120(pad 5000) x 1024, ld 1024
//   [4048000, 4179072)     X     256 x 2048,  ld 2048
//   [4179072, 4441216)     W_f   512 x 2048,  ld 2048
// ---------------------------------------------------------------------------
__global__ void fused_prep(
    const float* __restrict__ emb, const float* __restrict__ W_ih,
    const float* __restrict__ W_hh, const float* __restrict__ W_out,
    const float* __restrict__ X, const float* __restrict__ W_f,
    const int* __restrict__ labels,
    const float* __restrict__ b_ih, const float* __restrict__ b_hh,
    unsigned short* __restrict__ emb_bf, unsigned short* __restrict__ WihE_bf,
    unsigned short* __restrict__ WihA_bf, unsigned short* __restrict__ Whh_bf,
    unsigned short* __restrict__ Wout_bf,
    unsigned short* __restrict__ X_bf, unsigned short* __restrict__ Wf_bf,
    int* __restrict__ idxEmb, int* __restrict__ idxLog,
    float* __restrict__ bsum_perm)
{
    const int i = blockIdx.x * 256 + threadIdx.x;

    if (i < B_ * T_) {
        {
            int t = i >> 8, b = i & (B_ - 1);
            int tsrc = (t == 0) ? (T_ - 1) : (t - 1);
            idxEmb[i] = labels[b * T_ + tsrc];
        }
        {
            int b = i / T_, t = i % T_;
            idxLog[i] = (t + 1) * 16384 + b;
        }
    }
    if (i < G4_) {
        int w = ((i & 3) << 10) | (i >> 2);
        bsum_perm[i] = b_ih[w] + b_hh[w];
    }

    const float* src = nullptr;
    unsigned short* dst = nullptr;
    bool zero = false;
    if (i < 640128) {
        int r = i >> 7, c4 = i & 127;
        src = emb + (size_t)r * 512 + c4 * 4;
        dst = emb_bf + (size_t)r * 512 + c4 * 4;
    } else if (i < 1164416) {
        int j = i - 640128, r = j >> 7, c4 = j & 127;
        src = W_ih + (size_t)r * 1024 + 512 + c4 * 4;
        dst = WihE_bf + (size_t)r * 512 + c4 * 4;
    } else if (i < 1688704) {
        int j = i - 1164416, r = j >> 7, c4 = j & 127;
        src = W_ih + (size_t)r * 1024 + c4 * 4;
        dst = WihA_bf + (size_t)r * 512 + c4 * 4;
    } else if (i < 2737280) {
        int j = i - 1688704, r = j >> 8, c4 = j & 255;
        src = W_hh + (size_t)r * 1024 + c4 * 4;
        dst = Whh_bf + (size_t)r * 1024 + c4 * 4;
    } else if (i < 4048000) {
        int j = i - 2737280, r = j >> 8, c4 = j & 255;
        zero = (r >= V_);
        src = W_out + (size_t)r * 1024 + c4 * 4;
        dst = Wout_bf + (size_t)r * 1024 + c4 * 4;
    } else if (i < 4179072) {
        int j = i - 4048000, r = j >> 9, c4 = j & 511;
        src = X + (size_t)r * 2048 + c4 * 4;
        dst = X_bf + (size_t)r * 2048 + c4 * 4;
    } else if (i < 4441216) {
        int j = i - 4179072, r = j >> 9, c4 = j & 511;
        src = W_f + (size_t)r * 2048 + c4 * 4;
        dst = Wf_bf + (size_t)r * 2048 + c4 * 4;
    } else {
        return;
    }

    ushort4 o;
    if (!zero) {
        float4 v = *(const float4*)src;
        o.x = f2b(v.x); o.y = f2b(v.y); o.z = f2b(v.z); o.w = f2b(v.w);
    } else {
        o = make_ushort4(0, 0, 0, 0);
    }
    *(ushort4*)dst = o;
}

extern "C" void kernel_launch(void* const* d_in, const int* in_sizes, int n_in,
                              void* d_out, int out_size, void* d_ws, size_t ws_size,
                              hipStream_t stream)
{
    const float* X      = (const float*)d_in[0];
    const int*   labels = (const int*)  d_in[1];
    const float* W_f    = (const float*)d_in[2];
    const float* b_f    = (const float*)d_in[3];
    const float* emb    = (const float*)d_in[4];
    const float* W_ih   = (const float*)d_in[5];
    const float* W_hh   = (const float*)d_in[6];
    const float* b_ih   = (const float*)d_in[7];
    const float* b_hh   = (const float*)d_in[8];
    const float* W_out  = (const float*)d_in[9];
    const float* b_out  = (const float*)d_in[10];
    float* out = (float*)d_out;
    (void)in_sizes; (void)n_in; (void)out_size; (void)ws_size;

    char* ws = (char*)d_ws;
    size_t off = 0;
    auto alloc = [&](size_t bytes) {
        void* p = ws + off;
        off += (bytes + 255) & ~(size_t)255;
        return p;
    };
    unsigned short* emb_bf  = (unsigned short*)alloc((size_t)(V_ + 1) * E_ * 2);
    unsigned short* WihE_bf = (unsigned short*)alloc((size_t)G4_ * E_ * 2);
    unsigned short* WihA_bf = (unsigned short*)alloc((size_t)G4_ * E_ * 2);
    unsigned short* Whh_bf  = (unsigned short*)alloc((size_t)G4_ * H_ * 2);
    unsigned short* Wout_bf = (unsigned short*)alloc((size_t)5120 * H_ * 2);
    unsigned short* hs_bf   = (unsigned short*)alloc((size_t)(T_ + 1) * 262144 * 2);
    unsigned short* feat_bf = (unsigned short*)alloc((size_t)B_ * E_ * 2);
    float* bsum_perm = (float*)alloc(G4_ * 4);
    int*   idxEmb    = (int*)  alloc(B_ * T_ * 4);
    int*   idxLog    = (int*)  alloc(B_ * T_ * 4);
    unsigned int* flags = (unsigned int*)alloc((size_t)(T_ + 1) * 256 * 4);

    // d_out reuse: gates_bf [T,B,1024,4] bf16 (84 MB = 21M floats) at front,
    // consumed by the recurrence before the logits GEMM overwrites d_out;
    // baseMat (permuted-linear f32, 4 MB) at float-offset 22M; X_bf / Wf_bf
    // scratch at float-offsets 25M / 26M (dead after the features GEMM).
    unsigned short* gates_bf = (unsigned short*)out;
    float* baseMat = out + 22 * 1024 * 1024;
    unsigned short* X_bf  = (unsigned short*)(out + 25 * 1024 * 1024);
    unsigned short* Wf_bf = (unsigned short*)(out + 26 * 1024 * 1024);

    hipMemsetAsync(flags, 0, (size_t)(T_ + 1) * 256 * 4, stream);

    // fused conversions + indices + bias (4,441,216 ushort4 units)
    fused_prep<<<(4441216 + 255) / 256, 256, 0, stream>>>(
        emb, W_ih, W_hh, W_out, X, W_f, labels, b_ih, b_hh,
        emb_bf, WihE_bf, WihA_bf, Whh_bf, Wout_bf, X_bf, Wf_bf,
        idxEmb, idxLog, bsum_perm);

    // features (bf16) = X_bf @ Wf_bf^T + b_f   [256,512] K=2048 (MFMA)
    gemm_mfma<2><<<dim3(E_ / 128, B_ / 128), 256, 0, stream>>>(
        X_bf, IN_, 0, nullptr, Wf_bf, IN_, 0, b_f,
        nullptr, 0, 0, feat_bf, E_, E_, IN_);

    // baseMat (permuted-linear f32) = feat @ WihA(q-mapped)^T + bsum_perm
    gemm_mfma<0><<<dim3(G4_ / 128, B_ / 128), 256, 0, stream>>>(
        feat_bf, E_, 0, nullptr, WihA_bf, E_, 1, nullptr,
        bsum_perm, 0, 0, baseMat, G4_, G4_, E_);

    // gates_bf[t,b,hc,q] = gather(emb_bf) @ WihE(q-mapped)^T + baseMat[b]
    gemm_mfma<1><<<dim3(G4_ / 128, (B_ * T_) / 128), 256, 0, stream>>>(
        emb_bf, E_, 0, idxEmb, WihE_bf, E_, 1, nullptr,
        baseMat, B_ - 1, G4_, gates_bf, G4_, G4_, E_);

    // ---- persistent recurrence (all 40 steps, one plain launch) ----
    {
        hipFuncSetAttribute((const void*)recur_persist,
                            hipFuncAttributeMaxDynamicSharedMemorySize, 131072);
        recur_persist<<<256, 256, 131072, stream>>>(hs_bf, Whh_bf, gates_bf, flags);
    }

    // logits = gather(hs_bf blocked) @ W_out^T + b_out   [10240,5000] K=1024
    gemm_big<<<dim3(5120 / 128, 10240 / 256), 256, 0, stream>>>(
        hs_bf, idxLog, Wout_bf, b_out, out);
}

// Round 16
// 645.752 us; speedup vs baseline: 1.1759x; 1.1759x over previous
//
#include <hip/hip_runtime.h>
#include <hip/hip_bf16.h>
#include <math.h>

#define B_  256
#define T_  40
#define IN_ 2048
#define E_  512
#define H_  1024
#define V_  5000
#define G4_ 4096   // 4*H

typedef __bf16 bf16x8 __attribute__((ext_vector_type(8)));
typedef float  f32x4  __attribute__((ext_vector_type(4)));
typedef unsigned int u32x4 __attribute__((ext_vector_type(4)));
typedef unsigned short u16x8 __attribute__((ext_vector_type(8)));

__device__ __forceinline__ float sigm_f(float x) { return 1.0f / (1.0f + __expf(-x)); }
__device__ __forceinline__ float tanh_f(float x) { return 1.0f - 2.0f / (1.0f + __expf(2.0f * x)); }

__device__ __forceinline__ unsigned short f2b(float x) {
    __hip_bfloat16 h = __float2bfloat16(x);
    return *reinterpret_cast<unsigned short*>(&h);
}
__device__ __forceinline__ float b2f(unsigned short u) {
    unsigned int v = (unsigned int)u << 16;
    return __builtin_bit_cast(float, v);
}

#define GLOAD_LDS(g, l) __builtin_amdgcn_global_load_lds(                     \
    (const __attribute__((address_space(1))) unsigned int*)(g),               \
    (__attribute__((address_space(3))) unsigned int*)(l), 16, 0, 0)

// normal (L2-cached) 16B load, manual vmcnt accounting via VM_WAIT
__device__ __forceinline__ void l2_load16(u32x4* dst, const unsigned short* p) {
    asm volatile("global_load_dwordx4 %0, %1, off" : "=v"(*dst) : "v"(p));
}
// LLC-coherent (cross-XCD) stores + poll
__device__ __forceinline__ void llc_store16(unsigned short* p, u32x4 v) {
    asm volatile("global_store_dwordx4 %0, %1, off sc0 sc1" :: "v"(p), "v"(v) : "memory");
}
__device__ __forceinline__ void llc_store4(unsigned int* p, unsigned int v) {
    asm volatile("global_store_dword %0, %1, off sc0 sc1" :: "v"(p), "v"(v) : "memory");
}
// poll load: waitcnt INSIDE the asm (compiler doesn't track asm loads)
__device__ __forceinline__ unsigned int llc_load4_wait(const unsigned int* p) {
    unsigned int v;
    asm volatile("global_load_dword %0, %1, off sc0 sc1\n\ts_waitcnt vmcnt(0)"
                 : "=v"(v) : "v"(p) : "memory");
    return v;
}
#define VM_WAIT(n) do {                                                       \
    asm volatile("s_waitcnt vmcnt(" #n ")" ::: "memory");                     \
    __builtin_amdgcn_sched_barrier(0);                                        \
} while (0)

// ---------------------------------------------------------------------------
// bf16 MFMA GEMM, depth-2 counted-vmcnt pipeline (3 LDS buffers, one raw
// barrier per K-iter).
// C = gather(A) @ Bsel^T (+ bias) (+ addMat[(row&rowMask)*addStride + col])
// aBlocked: A stored as [kblk][256 rows][16] blocks (hs layout).
// bMapQ:    B row for (permuted) col c is (c&3)*1024 + (c>>2).
// OUTMODE 0: f32 store (bias/addMat in epilogue), col guarded by N.
// OUTMODE 1: bf16 store via LDS-staged coalesced 16B writes (N%128==0;
//            addMat applied; bias ignored).
// OUTMODE 2: bf16 scalar store + bias (small matrices).
// 128x128 tile, BK=32, 256 thr = 4 waves, 16x16x32 MFMA. LDS 48 KB static.
// ---------------------------------------------------------------------------
template<int OUTMODE>
__global__ __launch_bounds__(256) void gemm_mfma(
    const unsigned short* __restrict__ A, int lda, int aBlocked,
    const int* __restrict__ gidx,
    const unsigned short* __restrict__ Bm, int ldb, int bMapQ,
    const float* __restrict__ bias,
    const float* __restrict__ addMat, int rowMask, long long addStride,
    void* __restrict__ Cout, int ldc, int N, int K)
{
    __shared__ unsigned short SH[24576];   // A bufs [3][4096] | B bufs [3][4096]

    const int tid  = threadIdx.x;
    const int wave = tid >> 6, lane = tid & 63;
    const int brow0 = blockIdx.y * 128, bcol0 = blockIdx.x * 128;
    const int wrow0 = (wave >> 1) * 64, wcol0 = (wave & 1) * 64;

    const int srow = lane >> 2;
    const int scol = (lane & 3) * 8;
    const size_t kstep = aBlocked ? 256 : 1;
    const unsigned short *pA[2], *pB[2];
    int segoff[2];
    #pragma unroll
    for (int i = 0; i < 2; ++i) {
        int seg = wave * 2 + i;
        int row = seg * 16 + srow;
        long long ar = gidx ? (long long)gidx[brow0 + row] : (long long)(brow0 + row);
        if (aBlocked)
            pA[i] = A + ((size_t)ar << 4) + ((size_t)(scol >> 4) << 12) + (scol & 8);
        else
            pA[i] = A + (size_t)ar * lda + scol;
        int bc = bcol0 + row;
        long long wrow = bMapQ ? (long long)(((bc & 3) << 10) | (bc >> 2)) : bc;
        pB[i] = Bm + wrow * ldb + scol;
        segoff[i] = seg * 512;
    }

    f32x4 acc[4][4] = {};
    const int foff = (lane & 15) * 32 + (lane >> 4) * 8;

    #define STAGE(buf, k0)                                                    \
        GLOAD_LDS(pA[0] + (size_t)(k0) * kstep, SH + (buf) * 4096 + segoff[0]); \
        GLOAD_LDS(pA[1] + (size_t)(k0) * kstep, SH + (buf) * 4096 + segoff[1]); \
        GLOAD_LDS(pB[0] + (k0), SH + 12288 + (buf) * 4096 + segoff[0]);       \
        GLOAD_LDS(pB[1] + (k0), SH + 12288 + (buf) * 4096 + segoff[1]);

    STAGE(0, 0)
    STAGE(1, 32)

    int cur = 0;
    for (int k0 = 0; k0 < K; k0 += 32) {
        if (k0 + 32 < K) { VM_WAIT(4); } else { VM_WAIT(0); }
        __builtin_amdgcn_s_barrier();   // raw: no implicit vmcnt(0) drain

        if (k0 + 64 < K) {
            int nb = cur + 2; if (nb >= 3) nb -= 3;
            STAGE(nb, k0 + 64)
        }

        bf16x8 a[4], b[4];
        #pragma unroll
        for (int m = 0; m < 4; ++m)
            a[m] = *(const bf16x8*)&SH[cur * 4096 + (wrow0 + m * 16) * 32 + foff];
        #pragma unroll
        for (int n = 0; n < 4; ++n)
            b[n] = *(const bf16x8*)&SH[12288 + cur * 4096 + (wcol0 + n * 16) * 32 + foff];
        #pragma unroll
        for (int m = 0; m < 4; ++m)
            #pragma unroll
            for (int n = 0; n < 4; ++n)
                acc[m][n] = __builtin_amdgcn_mfma_f32_16x16x32_bf16(
                    a[m], b[n], acc[m][n], 0, 0, 0);

        ++cur; if (cur == 3) cur = 0;
    }
    #undef STAGE

    if (OUTMODE == 0) {
        #pragma unroll
        for (int m = 0; m < 4; ++m)
            #pragma unroll
            for (int j = 0; j < 4; ++j) {
                int row = brow0 + wrow0 + m * 16 + (lane >> 4) * 4 + j;
                const float* addRow = addMat
                    ? addMat + (long long)(row & rowMask) * addStride : nullptr;
                #pragma unroll
                for (int n = 0; n < 4; ++n) {
                    int col = bcol0 + wcol0 + n * 16 + (lane & 15);
                    if (col < N) {
                        float v = acc[m][n][j];
                        if (addRow) v += addRow[col];
                        if (bias)   v += bias[col];
                        ((float*)Cout)[(long long)row * ldc + col] = v;
                    }
                }
            }
    } else if (OUTMODE == 1) {
        // LDS-staged bf16 epilogue: reuse SH[0..16384) as the C tile
        __syncthreads();
        #pragma unroll
        for (int m = 0; m < 4; ++m)
            #pragma unroll
            for (int j = 0; j < 4; ++j) {
                int lr = wrow0 + m * 16 + (lane >> 4) * 4 + j;
                int row = brow0 + lr;
                const float* addRow = addMat + (long long)(row & rowMask) * addStride;
                #pragma unroll
                for (int n = 0; n < 4; ++n) {
                    int lc = wcol0 + n * 16 + (lane & 15);
                    SH[lr * 128 + lc] = f2b(acc[m][n][j] + addRow[bcol0 + lc]);
                }
            }
        __syncthreads();
        #pragma unroll
        for (int p = 0; p < 8; ++p) {
            int idx = p * 256 + tid;
            int lr = idx >> 4, lc8 = (idx & 15) * 8;
            *(u32x4*)((unsigned short*)Cout + (size_t)(brow0 + lr) * ldc +
                      bcol0 + lc8) = *(const u32x4*)&SH[lr * 128 + lc8];
        }
    } else {
        #pragma unroll
        for (int m = 0; m < 4; ++m)
            #pragma unroll
            for (int j = 0; j < 4; ++j) {
                int row = brow0 + wrow0 + m * 16 + (lane >> 4) * 4 + j;
                #pragma unroll
                for (int n = 0; n < 4; ++n) {
                    int col = bcol0 + wcol0 + n * 16 + (lane & 15);
                    if (col < N)
                        ((unsigned short*)Cout)[(long long)row * ldc + col] =
                            f2b(acc[m][n][j] + (bias ? bias[col] : 0.f));
                }
            }
    }
}

// ---------------------------------------------------------------------------
// Logits GEMM: BM=256 x BN=128 tile, K=1024. 256 thr = 4 waves (2x2), each
// wave 128x64 output (acc 8x4 frags). Depth-2 counted-vmcnt pipeline, 3 LDS
// buffers (72 KB), one raw barrier per K-iter, 6 global_load_lds per stage.
// A = hs blocked ([kblk][256 row][16]) gathered via gidx; B = Wout_bf padded.
// ---------------------------------------------------------------------------
__global__ __launch_bounds__(256, 2) void gemm_big(
    const unsigned short* __restrict__ A,
    const int* __restrict__ gidx,
    const unsigned short* __restrict__ Bm,     // [5120][1024] bf16 (padded)
    const float* __restrict__ bias,            // [5000]
    float* __restrict__ C)                     // [10240][5000] f32
{
    __shared__ unsigned short SA[3 * 8192];    // 48 KB: 3 bufs x (256x32)
    __shared__ unsigned short SB[3 * 4096];    // 24 KB: 3 bufs x (128x32)

    const int tid = threadIdx.x;
    const int wave = tid >> 6, lane = tid & 63;
    const int brow0 = blockIdx.y * 256, bcol0 = blockIdx.x * 128;
    const int wrow0 = (wave >> 1) * 128, wcol0 = (wave & 1) * 64;

    const int srow = lane >> 2;          // 0..15
    const int scol = (lane & 3) * 8;
    const unsigned short* pA[4];
    const unsigned short* pB[2];
    int aoff[4], boff[2];
    #pragma unroll
    for (int i = 0; i < 4; ++i) {
        int seg = wave * 4 + i;          // 0..15
        int row = seg * 16 + srow;       // 0..255
        long long ar = gidx[brow0 + row];
        pA[i] = A + ((size_t)ar << 4) + ((size_t)(scol >> 4) << 12) + (scol & 8);
        aoff[i] = seg * 512;
    }
    #pragma unroll
    for (int i = 0; i < 2; ++i) {
        int seg = wave * 2 + i;          // 0..7
        int row = seg * 16 + srow;       // 0..127
        pB[i] = Bm + (size_t)(bcol0 + row) * 1024 + scol;
        boff[i] = seg * 512;
    }

    f32x4 acc[8][4] = {};
    const int foff = (lane & 15) * 32 + (lane >> 4) * 8;

    #define BSTAGE(buf, k0)                                                   \
        GLOAD_LDS(pA[0] + (size_t)(k0) * 256, SA + (buf) * 8192 + aoff[0]);   \
        GLOAD_LDS(pA[1] + (size_t)(k0) * 256, SA + (buf) * 8192 + aoff[1]);   \
        GLOAD_LDS(pA[2] + (size_t)(k0) * 256, SA + (buf) * 8192 + aoff[2]);   \
        GLOAD_LDS(pA[3] + (size_t)(k0) * 256, SA + (buf) * 8192 + aoff[3]);   \
        GLOAD_LDS(pB[0] + (k0), SB + (buf) * 4096 + boff[0]);                 \
        GLOAD_LDS(pB[1] + (k0), SB + (buf) * 4096 + boff[1]);

    BSTAGE(0, 0)
    BSTAGE(1, 32)

    int cur = 0;
    for (int k0 = 0; k0 < 1024; k0 += 32) {
        if (k0 + 32 < 1024) { VM_WAIT(6); } else { VM_WAIT(0); }
        __builtin_amdgcn_s_barrier();

        if (k0 + 64 < 1024) {
            int nb = cur + 2; if (nb >= 3) nb -= 3;
            BSTAGE(nb, k0 + 64)
        }

        bf16x8 b[4];
        #pragma unroll
        for (int n = 0; n < 4; ++n)
            b[n] = *(const bf16x8*)&SB[cur * 4096 + (wcol0 + n * 16) * 32 + foff];
        #pragma unroll
        for (int m = 0; m < 8; ++m) {
            bf16x8 a = *(const bf16x8*)&SA[cur * 8192 + (wrow0 + m * 16) * 32 + foff];
            #pragma unroll
            for (int n = 0; n < 4; ++n)
                acc[m][n] = __builtin_amdgcn_mfma_f32_16x16x32_bf16(
                    a, b[n], acc[m][n], 0, 0, 0);
        }
        ++cur; if (cur == 3) cur = 0;
    }
    #undef BSTAGE

    #pragma unroll
    for (int m = 0; m < 8; ++m)
        #pragma unroll
        for (int j = 0; j < 4; ++j) {
            int row = brow0 + wrow0 + m * 16 + (lane >> 4) * 4 + j;
            float* orow = C + (size_t)row * 5000;
            #pragma unroll
            for (int n = 0; n < 4; ++n) {
                int col = bcol0 + wcol0 + n * 16 + (lane & 15);
                if (col < V_)
                    orow[col] = acc[m][n][j] + bias[col];
            }
        }
}

// ---------------------------------------------------------------------------
// Persistent LSTM recurrence (round-12/14 proven version, exact revert).
// 256 WGs x 256 thr. WG (mb = bid>>6, hb = bid&63): batch rows mb*64..+64,
// h-cols hb*16..+16. W_hh slice LDS-resident 128 KB XOR-swizzled; gates bf16
// quads [T][B][1024][4] prefetched one step ahead; h blocked
// [64 kblk][256 row][16]; per-wave flag sc0sc1 + 64-lane parallel poll.
// ---------------------------------------------------------------------------
__global__ __launch_bounds__(256) void recur_persist(
    unsigned short* __restrict__ hs,          // slots 1..40, each 262144 elems
    const unsigned short* __restrict__ Whh,   // [4096,1024] bf16
    const unsigned short* __restrict__ gates, // [T,B,1024,4] bf16 (quad)
    unsigned int* __restrict__ flags)         // [(T+1)*256], zeroed
{
    extern __shared__ unsigned short lds[];   // [64][1024] bf16 = 128 KB
    __shared__ unsigned short hstage[64][24];

    const int tid = threadIdx.x;
    const int w = tid >> 6, lane = tid & 63;
    const int mb = blockIdx.x >> 6;
    const int hb = blockIdx.x & 63;
    const int r16 = lane & 15, g4 = lane >> 4;
    const int sw7 = r16 & 7;
    const size_t SLOT = 262144;

    const int arow = mb * 64 + w * 16 + r16;
    const size_t abase = ((size_t)arow << 4) + ((g4 >> 1) << 12) + ((g4 & 1) << 3);
    const int orow0 = mb * 64 + w * 16 + g4 * 4;
    const int hc    = hb * 16 + r16;
    const int lrow0 = w * 16 + g4 * 4;
    const size_t gq_base = ((size_t)orow0 << 12) + ((size_t)hc << 2);

    ushort4 gqc[4], gqn[4];
    #pragma unroll
    for (int j = 0; j < 4; ++j)
        gqc[j] = *(const ushort4*)(gates + gq_base + ((size_t)j << 12));

    {
        const int q = w;
        for (int r = 0; r < 16; ++r) {
            const int g = q * 16 + r;
            const unsigned short* rowsrc =
                Whh + ((size_t)q * 1024 + hb * 16 + r) * H_;
            #pragma unroll
            for (int half = 0; half < 2; ++half) {
                int gran = (half * 64 + lane) ^ (g & 7);
                GLOAD_LDS(rowsrc + gran * 8, &lds[g * 1024 + half * 512]);
            }
        }
    }
    asm volatile("s_waitcnt vmcnt(0)" ::: "memory");
    __syncthreads();

    int qbase[4];
    #pragma unroll
    for (int q = 0; q < 4; ++q) qbase[q] = (q * 16 + r16) << 11;

    float cc[4];

    #define STORE_H(T1, HV)                                                   \
    {                                                                         \
        _Pragma("unroll")                                                     \
        for (int j = 0; j < 4; ++j) hstage[lrow0 + j][r16] = HV[j];           \
        __syncthreads();                                                      \
        if (w == 0) {                                                         \
            unsigned short* dst0 = hs + (size_t)(T1) * SLOT +                 \
                (((size_t)hb * 256 + mb * 64) << 4);                          \
            _Pragma("unroll")                                                 \
            for (int s = 0; s < 2; ++s) {                                     \
                int idx = s * 64 + lane;                                      \
                u32x4 v = *(const u32x4*)&hstage[idx >> 1][(idx & 1) * 8];    \
                llc_store16(dst0 + (size_t)idx * 8, v);                       \
            }                                                                 \
            asm volatile("s_waitcnt vmcnt(0)" ::: "memory");                  \
            if (lane == 0)                                                    \
                llc_store4(flags + ((T1) << 8) + (mb << 6) + hb, 1u);         \
        }                                                                     \
    }

    // step 0
    {
        #pragma unroll
        for (int j = 0; j < 4; ++j)
            gqn[j] = *(const ushort4*)(gates + (1ull << 20) + gq_base +
                                       ((size_t)j << 12));
        unsigned short hv[4];
        #pragma unroll
        for (int j = 0; j < 4; ++j) {
            float gi = b2f(gqc[j].x), gg = b2f(gqc[j].z), go = b2f(gqc[j].w);
            float c2 = sigm_f(gi) * tanh_f(gg);
            cc[j] = c2;
            hv[j] = f2b(sigm_f(go) * tanh_f(c2));
        }
        STORE_H(1, hv)
        #pragma unroll
        for (int j = 0; j < 4; ++j) gqc[j] = gqn[j];
    }

    for (int t = 1; t < T_; ++t) {
        {
            const unsigned int* fp = flags + ((size_t)t << 8) + (mb << 6) + lane;
            for (;;) {
                unsigned int fv = llc_load4_wait(fp);
                if (__all(fv == 1u)) break;
                __builtin_amdgcn_s_sleep(1);
            }
        }
        __builtin_amdgcn_sched_barrier(0);

        const unsigned short* hp = hs + (size_t)t * SLOT + abase;

        u32x4 a0[8], a1[8];
        #pragma unroll
        for (int u = 0; u < 8; ++u) l2_load16(&a0[u], hp + (size_t)u * 8192);
        #pragma unroll
        for (int u = 0; u < 8; ++u) l2_load16(&a1[u], hp + (size_t)(8 + u) * 8192);

        f32x4 acc[4] = {};

#define DO_CHUNK(BUF, KSB)                                                    \
        _Pragma("unroll")                                                     \
        for (int u = 0; u < 8; ++u) {                                         \
            bf16x8 a8 = __builtin_bit_cast(bf16x8, BUF[u]);                   \
            _Pragma("unroll")                                                 \
            for (int q = 0; q < 4; ++q) {                                     \
                int off = qbase[q] + (((((KSB) + u) * 4 + g4) ^ sw7) << 4);   \
                bf16x8 b8 = *(const bf16x8*)((const char*)lds + off);         \
                acc[q] = __builtin_amdgcn_mfma_f32_16x16x32_bf16(             \
                    a8, b8, acc[q], 0, 0, 0);                                 \
            }                                                                 \
        }

        VM_WAIT(8);
        DO_CHUNK(a0, 0)
        #pragma unroll
        for (int u = 0; u < 8; ++u) l2_load16(&a0[u], hp + (size_t)(16 + u) * 8192);
        VM_WAIT(8);
        DO_CHUNK(a1, 8)
        #pragma unroll
        for (int u = 0; u < 8; ++u) l2_load16(&a1[u], hp + (size_t)(24 + u) * 8192);
        VM_WAIT(8);
        DO_CHUNK(a0, 16)
        VM_WAIT(0);
        DO_CHUNK(a1, 24)
#undef DO_CHUNK

        if (t + 1 < T_) {
            #pragma unroll
            for (int j = 0; j < 4; ++j)
                gqn[j] = *(const ushort4*)(gates +
                    ((size_t)(t + 1) << 20) + gq_base + ((size_t)j << 12));
        }

        unsigned short hv[4];
        #pragma unroll
        for (int j = 0; j < 4; ++j) {
            float gi = acc[0][j] + b2f(gqc[j].x);
            float gf = acc[1][j] + b2f(gqc[j].y);
            float gg = acc[2][j] + b2f(gqc[j].z);
            float go = acc[3][j] + b2f(gqc[j].w);
            float c2 = sigm_f(gf) * cc[j] + sigm_f(gi) * tanh_f(gg);
            cc[j] = c2;
            hv[j] = f2b(sigm_f(go) * tanh_f(c2));
        }
        STORE_H(t + 1, hv)
        #pragma unroll
        for (int j = 0; j < 4; ++j) gqc[j] = gqn[j];
    }
    #undef STORE_H
}

// ---------------------------------------------------------------------------
// Fused prep: ALL bf16 conversions (incl. X and W_f) + gather indices +
// permuted bias in ONE kernel. Segments in ushort4 units:
//   [0, 640128)            emb   5001 x 512,  ld 512,  col0 0
//   [640128, 1164416)      WihE  4096 x 512,  ld 1024, col0 512
//   [1164416, 1688704)     WihA  4096 x 512,  ld 1024, col0 0
//   [1688704, 2737280)     Whh   4096 x 1024, ld 1024
//   [2737280, 4048000)     Wout  5120(pad 5000) x 1024, ld 1024
//   [4048000, 4179072)     X     256 x 2048,  ld 2048
//   [4179072, 4441216)     W_f   512 x 2048,  ld 2048
// ---------------------------------------------------------------------------
__global__ void fused_prep(
    const float* __restrict__ emb, const float* __restrict__ W_ih,
    const float* __restrict__ W_hh, const float* __restrict__ W_out,
    const float* __restrict__ X, const float* __restrict__ W_f,
    const int* __restrict__ labels,
    const float* __restrict__ b_ih, const float* __restrict__ b_hh,
    unsigned short* __restrict__ emb_bf, unsigned short* __restrict__ WihE_bf,
    unsigned short* __restrict__ WihA_bf, unsigned short* __restrict__ Whh_bf,
    unsigned short* __restrict__ Wout_bf,
    unsigned short* __restrict__ X_bf, unsigned short* __restrict__ Wf_bf,
    int* __restrict__ idxEmb, int* __restrict__ idxLog,
    float* __restrict__ bsum_perm)
{
    const int i = blockIdx.x * 256 + threadIdx.x;

    if (i < B_ * T_) {
        {
            int t = i >> 8, b = i & (B_ - 1);
            int tsrc = (t == 0) ? (T_ - 1) : (t - 1);
            idxEmb[i] = labels[b * T_ + tsrc];
        }
        {
            int b = i / T_, t = i % T_;
            idxLog[i] = (t + 1) * 16384 + b;
        }
    }
    if (i < G4_) {
        int w = ((i & 3) << 10) | (i >> 2);
        bsum_perm[i] = b_ih[w] + b_hh[w];
    }

    const float* src = nullptr;
    unsigned short* dst = nullptr;
    bool zero = false;
    if (i < 640128) {
        int r = i >> 7, c4 = i & 127;
        src = emb + (size_t)r * 512 + c4 * 4;
        dst = emb_bf + (size_t)r * 512 + c4 * 4;
    } else if (i < 1164416) {
        int j = i - 640128, r = j >> 7, c4 = j & 127;
        src = W_ih + (size_t)r * 1024 + 512 + c4 * 4;
        dst = WihE_bf + (size_t)r * 512 + c4 * 4;
    } else if (i < 1688704) {
        int j = i - 1164416, r = j >> 7, c4 = j & 127;
        src = W_ih + (size_t)r * 1024 + c4 * 4;
        dst = WihA_bf + (size_t)r * 512 + c4 * 4;
    } else if (i < 2737280) {
        int j = i - 1688704, r = j >> 8, c4 = j & 255;
        src = W_hh + (size_t)r * 1024 + c4 * 4;
        dst = Whh_bf + (size_t)r * 1024 + c4 * 4;
    } else if (i < 4048000) {
        int j = i - 2737280, r = j >> 8, c4 = j & 255;
        zero = (r >= V_);
        src = W_out + (size_t)r * 1024 + c4 * 4;
        dst = Wout_bf + (size_t)r * 1024 + c4 * 4;
    } else if (i < 4179072) {
        int j = i - 4048000, r = j >> 9, c4 = j & 511;
        src = X + (size_t)r * 2048 + c4 * 4;
        dst = X_bf + (size_t)r * 2048 + c4 * 4;
    } else if (i < 4441216) {
        int j = i - 4179072, r = j >> 9, c4 = j & 511;
        src = W_f + (size_t)r * 2048 + c4 * 4;
        dst = Wf_bf + (size_t)r * 2048 + c4 * 4;
    } else {
        return;
    }

    ushort4 o;
    if (!zero) {
        float4 v = *(const float4*)src;
        o.x = f2b(v.x); o.y = f2b(v.y); o.z = f2b(v.z); o.w = f2b(v.w);
    } else {
        o = make_ushort4(0, 0, 0, 0);
    }
    *(ushort4*)dst = o;
}

extern "C" void kernel_launch(void* const* d_in, const int* in_sizes, int n_in,
                              void* d_out, int out_size, void* d_ws, size_t ws_size,
                              hipStream_t stream)
{
    const float* X      = (const float*)d_in[0];
    const int*   labels = (const int*)  d_in[1];
    const float* W_f    = (const float*)d_in[2];
    const float* b_f    = (const float*)d_in[3];
    const float* emb    = (const float*)d_in[4];
    const float* W_ih   = (const float*)d_in[5];
    const float* W_hh   = (const float*)d_in[6];
    const float* b_ih   = (const float*)d_in[7];
    const float* b_hh   = (const float*)d_in[8];
    const float* W_out  = (const float*)d_in[9];
    const float* b_out  = (const float*)d_in[10];
    float* out = (float*)d_out;
    (void)in_sizes; (void)n_in; (void)out_size; (void)ws_size;

    char* ws = (char*)d_ws;
    size_t off = 0;
    auto alloc = [&](size_t bytes) {
        void* p = ws + off;
        off += (bytes + 255) & ~(size_t)255;
        return p;
    };
    unsigned short* emb_bf  = (unsigned short*)alloc((size_t)(V_ + 1) * E_ * 2);
    unsigned short* WihE_bf = (unsigned short*)alloc((size_t)G4_ * E_ * 2);
    unsigned short* WihA_bf = (unsigned short*)alloc((size_t)G4_ * E_ * 2);
    unsigned short* Whh_bf  = (unsigned short*)alloc((size_t)G4_ * H_ * 2);
    unsigned short* Wout_bf = (unsigned short*)alloc((size_t)5120 * H_ * 2);
    unsigned short* hs_bf   = (unsigned short*)alloc((size_t)(T_ + 1) * 262144 * 2);
    unsigned short* feat_bf = (unsigned short*)alloc((size_t)B_ * E_ * 2);
    float* bsum_perm = (float*)alloc(G4_ * 4);
    int*   idxEmb    = (int*)  alloc(B_ * T_ * 4);
    int*   idxLog    = (int*)  alloc(B_ * T_ * 4);
    unsigned int* flags = (unsigned int*)alloc((size_t)(T_ + 1) * 256 * 4);

    // d_out reuse: gates_bf [T,B,1024,4] bf16 (84 MB = 21M floats) at front,
    // consumed by the recurrence before the logits GEMM overwrites d_out;
    // baseMat (permuted-linear f32, 4 MB) at float-offset 22M; X_bf / Wf_bf
    // scratch at float-offsets 25M / 26M (dead after the features GEMM).
    unsigned short* gates_bf = (unsigned short*)out;
    float* baseMat = out + 22 * 1024 * 1024;
    unsigned short* X_bf  = (unsigned short*)(out + 25 * 1024 * 1024);
    unsigned short* Wf_bf = (unsigned short*)(out + 26 * 1024 * 1024);

    hipMemsetAsync(flags, 0, (size_t)(T_ + 1) * 256 * 4, stream);

    // fused conversions + indices + bias (4,441,216 ushort4 units)
    fused_prep<<<(4441216 + 255) / 256, 256, 0, stream>>>(
        emb, W_ih, W_hh, W_out, X, W_f, labels, b_ih, b_hh,
        emb_bf, WihE_bf, WihA_bf, Whh_bf, Wout_bf, X_bf, Wf_bf,
        idxEmb, idxLog, bsum_perm);

    // features (bf16) = X_bf @ Wf_bf^T + b_f   [256,512] K=2048 (MFMA)
    gemm_mfma<2><<<dim3(E_ / 128, B_ / 128), 256, 0, stream>>>(
        X_bf, IN_, 0, nullptr, Wf_bf, IN_, 0, b_f,
        nullptr, 0, 0, feat_bf, E_, E_, IN_);

    // baseMat (permuted-linear f32) = feat @ WihA(q-mapped)^T + bsum_perm
    gemm_mfma<0><<<dim3(G4_ / 128, B_ / 128), 256, 0, stream>>>(
        feat_bf, E_, 0, nullptr, WihA_bf, E_, 1, nullptr,
        bsum_perm, 0, 0, baseMat, G4_, G4_, E_);

    // gates_bf[t,b,hc,q] = gather(emb_bf) @ WihE(q-mapped)^T + baseMat[b]
    gemm_mfma<1><<<dim3(G4_ / 128, (B_ * T_) / 128), 256, 0, stream>>>(
        emb_bf, E_, 0, idxEmb, WihE_bf, E_, 1, nullptr,
        baseMat, B_ - 1, G4_, gates_bf, G4_, G4_, E_);

    // ---- persistent recurrence (all 40 steps, one plain launch) ----
    {
        hipFuncSetAttribute((const void*)recur_persist,
                            hipFuncAttributeMaxDynamicSharedMemorySize, 131072);
        recur_persist<<<256, 256, 131072, stream>>>(hs_bf, Whh_bf, gates_bf, flags);
    }

    // logits = gather(hs_bf blocked) @ W_out^T + b_out   [10240,5000] K=1024
    gemm_big<<<dim3(5120 / 128, 10240 / 256), 256, 0, stream>>>(
        hs_bf, idxLog, Wout_bf, b_out, out);
}

// Round 17
// 637.608 us; speedup vs baseline: 1.1909x; 1.0128x over previous
//
#include <hip/hip_runtime.h>
#include <hip/hip_bf16.h>
#include <math.h>

#define B_  256
#define T_  40
#define IN_ 2048
#define E_  512
#define H_  1024
#define V_  5000
#define G4_ 4096   // 4*H

typedef __bf16 bf16x8 __attribute__((ext_vector_type(8)));
typedef float  f32x4  __attribute__((ext_vector_type(4)));
typedef unsigned int u32x4 __attribute__((ext_vector_type(4)));
typedef unsigned short u16x8 __attribute__((ext_vector_type(8)));

__device__ __forceinline__ float sigm_f(float x) { return 1.0f / (1.0f + __expf(-x)); }
__device__ __forceinline__ float tanh_f(float x) { return 1.0f - 2.0f / (1.0f + __expf(2.0f * x)); }

__device__ __forceinline__ unsigned short f2b(float x) {
    __hip_bfloat16 h = __float2bfloat16(x);
    return *reinterpret_cast<unsigned short*>(&h);
}
__device__ __forceinline__ float b2f(unsigned short u) {
    unsigned int v = (unsigned int)u << 16;
    return __builtin_bit_cast(float, v);
}

#define GLOAD_LDS(g, l) __builtin_amdgcn_global_load_lds(                     \
    (const __attribute__((address_space(1))) unsigned int*)(g),               \
    (__attribute__((address_space(3))) unsigned int*)(l), 16, 0, 0)

// normal (L2-cached) 16B load, manual vmcnt accounting
__device__ __forceinline__ void l2_load16(u32x4* dst, const unsigned short* p) {
    asm volatile("global_load_dwordx4 %0, %1, off" : "=v"(*dst) : "v"(p));
}
// LLC-coherent (cross-XCD) stores + poll
__device__ __forceinline__ void llc_store16(unsigned short* p, u32x4 v) {
    asm volatile("global_store_dwordx4 %0, %1, off sc0 sc1" :: "v"(p), "v"(v) : "memory");
}
__device__ __forceinline__ void llc_store4(unsigned int* p, unsigned int v) {
    asm volatile("global_store_dword %0, %1, off sc0 sc1" :: "v"(p), "v"(v) : "memory");
}
// poll load: waitcnt INSIDE the asm (compiler doesn't track asm loads)
__device__ __forceinline__ unsigned int llc_load4_wait(const unsigned int* p) {
    unsigned int v;
    asm volatile("global_load_dword %0, %1, off sc0 sc1\n\ts_waitcnt vmcnt(0)"
                 : "=v"(v) : "v"(p) : "memory");
    return v;
}
#define VM_WAIT(n) do {                                                       \
    asm volatile("s_waitcnt vmcnt(" #n ")" ::: "memory");                     \
    __builtin_amdgcn_sched_barrier(0);                                        \
} while (0)

// ---------------------------------------------------------------------------
// bf16 MFMA GEMM, depth-2 counted-vmcnt pipeline (3 LDS buffers, one raw
// barrier per K-iter). (unchanged from round 16)
// ---------------------------------------------------------------------------
template<int OUTMODE>
__global__ __launch_bounds__(256) void gemm_mfma(
    const unsigned short* __restrict__ A, int lda, int aBlocked,
    const int* __restrict__ gidx,
    const unsigned short* __restrict__ Bm, int ldb, int bMapQ,
    const float* __restrict__ bias,
    const float* __restrict__ addMat, int rowMask, long long addStride,
    void* __restrict__ Cout, int ldc, int N, int K)
{
    __shared__ unsigned short SH[24576];   // A bufs [3][4096] | B bufs [3][4096]

    const int tid  = threadIdx.x;
    const int wave = tid >> 6, lane = tid & 63;
    const int brow0 = blockIdx.y * 128, bcol0 = blockIdx.x * 128;
    const int wrow0 = (wave >> 1) * 64, wcol0 = (wave & 1) * 64;

    const int srow = lane >> 2;
    const int scol = (lane & 3) * 8;
    const size_t kstep = aBlocked ? 256 : 1;
    const unsigned short *pA[2], *pB[2];
    int segoff[2];
    #pragma unroll
    for (int i = 0; i < 2; ++i) {
        int seg = wave * 2 + i;
        int row = seg * 16 + srow;
        long long ar = gidx ? (long long)gidx[brow0 + row] : (long long)(brow0 + row);
        if (aBlocked)
            pA[i] = A + ((size_t)ar << 4) + ((size_t)(scol >> 4) << 12) + (scol & 8);
        else
            pA[i] = A + (size_t)ar * lda + scol;
        int bc = bcol0 + row;
        long long wrow = bMapQ ? (long long)(((bc & 3) << 10) | (bc >> 2)) : bc;
        pB[i] = Bm + wrow * ldb + scol;
        segoff[i] = seg * 512;
    }

    f32x4 acc[4][4] = {};
    const int foff = (lane & 15) * 32 + (lane >> 4) * 8;

    #define STAGE(buf, k0)                                                    \
        GLOAD_LDS(pA[0] + (size_t)(k0) * kstep, SH + (buf) * 4096 + segoff[0]); \
        GLOAD_LDS(pA[1] + (size_t)(k0) * kstep, SH + (buf) * 4096 + segoff[1]); \
        GLOAD_LDS(pB[0] + (k0), SH + 12288 + (buf) * 4096 + segoff[0]);       \
        GLOAD_LDS(pB[1] + (k0), SH + 12288 + (buf) * 4096 + segoff[1]);

    STAGE(0, 0)
    STAGE(1, 32)

    int cur = 0;
    for (int k0 = 0; k0 < K; k0 += 32) {
        if (k0 + 32 < K) { VM_WAIT(4); } else { VM_WAIT(0); }
        __builtin_amdgcn_s_barrier();   // raw: no implicit vmcnt(0) drain

        if (k0 + 64 < K) {
            int nb = cur + 2; if (nb >= 3) nb -= 3;
            STAGE(nb, k0 + 64)
        }

        bf16x8 a[4], b[4];
        #pragma unroll
        for (int m = 0; m < 4; ++m)
            a[m] = *(const bf16x8*)&SH[cur * 4096 + (wrow0 + m * 16) * 32 + foff];
        #pragma unroll
        for (int n = 0; n < 4; ++n)
            b[n] = *(const bf16x8*)&SH[12288 + cur * 4096 + (wcol0 + n * 16) * 32 + foff];
        #pragma unroll
        for (int m = 0; m < 4; ++m)
            #pragma unroll
            for (int n = 0; n < 4; ++n)
                acc[m][n] = __builtin_amdgcn_mfma_f32_16x16x32_bf16(
                    a[m], b[n], acc[m][n], 0, 0, 0);

        ++cur; if (cur == 3) cur = 0;
    }
    #undef STAGE

    if (OUTMODE == 0) {
        #pragma unroll
        for (int m = 0; m < 4; ++m)
            #pragma unroll
            for (int j = 0; j < 4; ++j) {
                int row = brow0 + wrow0 + m * 16 + (lane >> 4) * 4 + j;
                const float* addRow = addMat
                    ? addMat + (long long)(row & rowMask) * addStride : nullptr;
                #pragma unroll
                for (int n = 0; n < 4; ++n) {
                    int col = bcol0 + wcol0 + n * 16 + (lane & 15);
                    if (col < N) {
                        float v = acc[m][n][j];
                        if (addRow) v += addRow[col];
                        if (bias)   v += bias[col];
                        ((float*)Cout)[(long long)row * ldc + col] = v;
                    }
                }
            }
    } else if (OUTMODE == 1) {
        __syncthreads();
        #pragma unroll
        for (int m = 0; m < 4; ++m)
            #pragma unroll
            for (int j = 0; j < 4; ++j) {
                int lr = wrow0 + m * 16 + (lane >> 4) * 4 + j;
                int row = brow0 + lr;
                const float* addRow = addMat + (long long)(row & rowMask) * addStride;
                #pragma unroll
                for (int n = 0; n < 4; ++n) {
                    int lc = wcol0 + n * 16 + (lane & 15);
                    SH[lr * 128 + lc] = f2b(acc[m][n][j] + addRow[bcol0 + lc]);
                }
            }
        __syncthreads();
        #pragma unroll
        for (int p = 0; p < 8; ++p) {
            int idx = p * 256 + tid;
            int lr = idx >> 4, lc8 = (idx & 15) * 8;
            *(u32x4*)((unsigned short*)Cout + (size_t)(brow0 + lr) * ldc +
                      bcol0 + lc8) = *(const u32x4*)&SH[lr * 128 + lc8];
        }
    } else {
        #pragma unroll
        for (int m = 0; m < 4; ++m)
            #pragma unroll
            for (int j = 0; j < 4; ++j) {
                int row = brow0 + wrow0 + m * 16 + (lane >> 4) * 4 + j;
                #pragma unroll
                for (int n = 0; n < 4; ++n) {
                    int col = bcol0 + wcol0 + n * 16 + (lane & 15);
                    if (col < N)
                        ((unsigned short*)Cout)[(long long)row * ldc + col] =
                            f2b(acc[m][n][j] + (bias ? bias[col] : 0.f));
                }
            }
    }
}

// ---------------------------------------------------------------------------
// Logits GEMM: BM=256 x BN=128, K=1024 (unchanged from round 16).
// ---------------------------------------------------------------------------
__global__ __launch_bounds__(256, 2) void gemm_big(
    const unsigned short* __restrict__ A,
    const int* __restrict__ gidx,
    const unsigned short* __restrict__ Bm,     // [5120][1024] bf16 (padded)
    const float* __restrict__ bias,            // [5000]
    float* __restrict__ C)                     // [10240][5000] f32
{
    __shared__ unsigned short SA[3 * 8192];    // 48 KB
    __shared__ unsigned short SB[3 * 4096];    // 24 KB

    const int tid = threadIdx.x;
    const int wave = tid >> 6, lane = tid & 63;
    const int brow0 = blockIdx.y * 256, bcol0 = blockIdx.x * 128;
    const int wrow0 = (wave >> 1) * 128, wcol0 = (wave & 1) * 64;

    const int srow = lane >> 2;
    const int scol = (lane & 3) * 8;
    const unsigned short* pA[4];
    const unsigned short* pB[2];
    int aoff[4], boff[2];
    #pragma unroll
    for (int i = 0; i < 4; ++i) {
        int seg = wave * 4 + i;
        int row = seg * 16 + srow;
        long long ar = gidx[brow0 + row];
        pA[i] = A + ((size_t)ar << 4) + ((size_t)(scol >> 4) << 12) + (scol & 8);
        aoff[i] = seg * 512;
    }
    #pragma unroll
    for (int i = 0; i < 2; ++i) {
        int seg = wave * 2 + i;
        int row = seg * 16 + srow;
        pB[i] = Bm + (size_t)(bcol0 + row) * 1024 + scol;
        boff[i] = seg * 512;
    }

    f32x4 acc[8][4] = {};
    const int foff = (lane & 15) * 32 + (lane >> 4) * 8;

    #define BSTAGE(buf, k0)                                                   \
        GLOAD_LDS(pA[0] + (size_t)(k0) * 256, SA + (buf) * 8192 + aoff[0]);   \
        GLOAD_LDS(pA[1] + (size_t)(k0) * 256, SA + (buf) * 8192 + aoff[1]);   \
        GLOAD_LDS(pA[2] + (size_t)(k0) * 256, SA + (buf) * 8192 + aoff[2]);   \
        GLOAD_LDS(pA[3] + (size_t)(k0) * 256, SA + (buf) * 8192 + aoff[3]);   \
        GLOAD_LDS(pB[0] + (k0), SB + (buf) * 4096 + boff[0]);                 \
        GLOAD_LDS(pB[1] + (k0), SB + (buf) * 4096 + boff[1]);

    BSTAGE(0, 0)
    BSTAGE(1, 32)

    int cur = 0;
    for (int k0 = 0; k0 < 1024; k0 += 32) {
        if (k0 + 32 < 1024) { VM_WAIT(6); } else { VM_WAIT(0); }
        __builtin_amdgcn_s_barrier();

        if (k0 + 64 < 1024) {
            int nb = cur + 2; if (nb >= 3) nb -= 3;
            BSTAGE(nb, k0 + 64)
        }

        bf16x8 b[4];
        #pragma unroll
        for (int n = 0; n < 4; ++n)
            b[n] = *(const bf16x8*)&SB[cur * 4096 + (wcol0 + n * 16) * 32 + foff];
        #pragma unroll
        for (int m = 0; m < 8; ++m) {
            bf16x8 a = *(const bf16x8*)&SA[cur * 8192 + (wrow0 + m * 16) * 32 + foff];
            #pragma unroll
            for (int n = 0; n < 4; ++n)
                acc[m][n] = __builtin_amdgcn_mfma_f32_16x16x32_bf16(
                    a, b[n], acc[m][n], 0, 0, 0);
        }
        ++cur; if (cur == 3) cur = 0;
    }
    #undef BSTAGE

    #pragma unroll
    for (int m = 0; m < 8; ++m)
        #pragma unroll
        for (int j = 0; j < 4; ++j) {
            int row = brow0 + wrow0 + m * 16 + (lane >> 4) * 4 + j;
            float* orow = C + (size_t)row * 5000;
            #pragma unroll
            for (int n = 0; n < 4; ++n) {
                int col = bcol0 + wcol0 + n * 16 + (lane & 15);
                if (col < V_)
                    orow[col] = acc[m][n][j] + bias[col];
            }
        }
}

// ---------------------------------------------------------------------------
// Persistent LSTM recurrence v7: incremental K-group polling + 2-deep gates
// prefetch issued AFTER the flag store (out of the ack chain).
// 256 WGs x 256 thr. WG (mb = bid>>6, hb = bid&63). W_hh slice 128 KB LDS,
// XOR-swizzled. Consumer processes K in 4 chunks of 8 u-slices; chunk g only
// needs producers 16g..16g+15 (u-slice u covers kblks {2u,2u+1}), so flags
// are polled per group of 16, just-in-time, interleaved with h-load issue
// and MFMA. The poll's internal vmcnt(0) doubles as the h-load drain (all
// waits are vmcnt(0) -> robust to compiler-tracked loads). Producer protocol
// unchanged: hstage -> wave0 128x16B sc0sc1 stores -> vmcnt(0) ack -> flag.
// ---------------------------------------------------------------------------
__global__ __launch_bounds__(256) void recur_persist(
    unsigned short* __restrict__ hs,          // slots 1..40, each 262144 elems
    const unsigned short* __restrict__ Whh,   // [4096,1024] bf16
    const unsigned short* __restrict__ gates, // [T,B,1024,4] bf16 (quad)
    unsigned int* __restrict__ flags)         // [(T+1)*256], zeroed
{
    extern __shared__ unsigned short lds[];   // [64][1024] bf16 = 128 KB
    __shared__ unsigned short hstage[64][24];

    const int tid = threadIdx.x;
    const int w = tid >> 6, lane = tid & 63;
    const int mb = blockIdx.x >> 6;
    const int hb = blockIdx.x & 63;
    const int r16 = lane & 15, g4 = lane >> 4;
    const int sw7 = r16 & 7;
    const size_t SLOT = 262144;

    const int arow = mb * 64 + w * 16 + r16;
    const size_t abase = ((size_t)arow << 4) + ((g4 >> 1) << 12) + ((g4 & 1) << 3);
    const int orow0 = mb * 64 + w * 16 + g4 * 4;
    const int hc    = hb * 16 + r16;
    const int lrow0 = w * 16 + g4 * 4;
    const size_t gq_base = ((size_t)orow0 << 12) + ((size_t)hc << 2);

    // 2-deep gates pipeline: gq0 = gates[t], gq1 = gates[t+1]
    ushort4 gq0[4], gq1[4], gq2[4];
    #pragma unroll
    for (int j = 0; j < 4; ++j) {
        gq0[j] = *(const ushort4*)(gates + gq_base + ((size_t)j << 12));
        gq1[j] = *(const ushort4*)(gates + (1ull << 20) + gq_base + ((size_t)j << 12));
    }

    {
        const int q = w;
        for (int r = 0; r < 16; ++r) {
            const int g = q * 16 + r;
            const unsigned short* rowsrc =
                Whh + ((size_t)q * 1024 + hb * 16 + r) * H_;
            #pragma unroll
            for (int half = 0; half < 2; ++half) {
                int gran = (half * 64 + lane) ^ (g & 7);
                GLOAD_LDS(rowsrc + gran * 8, &lds[g * 1024 + half * 512]);
            }
        }
    }
    asm volatile("s_waitcnt vmcnt(0)" ::: "memory");
    __syncthreads();

    int qbase[4];
    #pragma unroll
    for (int q = 0; q < 4; ++q) qbase[q] = (q * 16 + r16) << 11;

    float cc[4];

    #define STORE_H(T1, HV)                                                   \
    {                                                                         \
        _Pragma("unroll")                                                     \
        for (int j = 0; j < 4; ++j) hstage[lrow0 + j][r16] = HV[j];           \
        __syncthreads();                                                      \
        if (w == 0) {                                                         \
            unsigned short* dst0 = hs + (size_t)(T1) * SLOT +                 \
                (((size_t)hb * 256 + mb * 64) << 4);                          \
            _Pragma("unroll")                                                 \
            for (int s = 0; s < 2; ++s) {                                     \
                int idx = s * 64 + lane;                                      \
                u32x4 v = *(const u32x4*)&hstage[idx >> 1][(idx & 1) * 8];    \
                llc_store16(dst0 + (size_t)idx * 8, v);                       \
            }                                                                 \
            asm volatile("s_waitcnt vmcnt(0)" ::: "memory");                  \
            if (lane == 0)                                                    \
                llc_store4(flags + ((T1) << 8) + (mb << 6) + hb, 1u);         \
        }                                                                     \
    }

    // group poll: producers (mb, G*16 .. G*16+15); 16 flags, 4x duplicated
    #define POLL_GROUP(T, G)                                                  \
    {                                                                         \
        const unsigned int* fp = flags + ((size_t)(T) << 8) + (mb << 6) +     \
                                 (G) * 16 + (lane & 15);                      \
        for (;;) {                                                            \
            unsigned int fv = llc_load4_wait(fp);                             \
            if (__all(fv == 1u)) break;                                       \
            __builtin_amdgcn_s_sleep(1);                                      \
        }                                                                     \
        __builtin_amdgcn_sched_barrier(0);                                    \
    }

    // ---- step 0: h0 = 0 -> gates only ----
    {
        unsigned short hv[4];
        #pragma unroll
        for (int j = 0; j < 4; ++j) {
            float gi = b2f(gq0[j].x), gg = b2f(gq0[j].z), go = b2f(gq0[j].w);
            float c2 = sigm_f(gi) * tanh_f(gg);
            cc[j] = c2;
            hv[j] = f2b(sigm_f(go) * tanh_f(c2));
        }
        STORE_H(1, hv)
        // prefetch gates[2] AFTER the flag store (out of the ack chain)
        #pragma unroll
        for (int j = 0; j < 4; ++j)
            gq2[j] = *(const ushort4*)(gates + (2ull << 20) + gq_base +
                                       ((size_t)j << 12));
        #pragma unroll
        for (int j = 0; j < 4; ++j) { gq0[j] = gq1[j]; gq1[j] = gq2[j]; }
    }

    // ---- steps 1..39 ----
    for (int t = 1; t < T_; ++t) {
        const unsigned short* hp = hs + (size_t)t * SLOT + abase;
        u32x4 a0[8], a1[8];

#define DO_CHUNK(BUF, KSB)                                                    \
        _Pragma("unroll")                                                     \
        for (int u = 0; u < 8; ++u) {                                         \
            bf16x8 a8 = __builtin_bit_cast(bf16x8, BUF[u]);                   \
            _Pragma("unroll")                                                 \
            for (int q = 0; q < 4; ++q) {                                     \
                int off = qbase[q] + (((((KSB) + u) * 4 + g4) ^ sw7) << 4);   \
                bf16x8 b8 = *(const bf16x8*)((const char*)lds + off);         \
                acc[q] = __builtin_amdgcn_mfma_f32_16x16x32_bf16(             \
                    a8, b8, acc[q], 0, 0, 0);                                 \
            }                                                                 \
        }

        POLL_GROUP(t, 0)
        #pragma unroll
        for (int u = 0; u < 8; ++u) l2_load16(&a0[u], hp + (size_t)u * 8192);
        POLL_GROUP(t, 1)            // vmcnt(0) inside drains a0 too
        #pragma unroll
        for (int u = 0; u < 8; ++u) l2_load16(&a1[u], hp + (size_t)(8 + u) * 8192);

        f32x4 acc[4] = {};
        DO_CHUNK(a0, 0)
        POLL_GROUP(t, 2)            // drains a1
        #pragma unroll
        for (int u = 0; u < 8; ++u) l2_load16(&a0[u], hp + (size_t)(16 + u) * 8192);
        DO_CHUNK(a1, 8)
        POLL_GROUP(t, 3)            // drains a0 (u16..23)
        #pragma unroll
        for (int u = 0; u < 8; ++u) l2_load16(&a1[u], hp + (size_t)(24 + u) * 8192);
        DO_CHUNK(a0, 16)
        VM_WAIT(0);
        DO_CHUNK(a1, 24)
#undef DO_CHUNK

        // ---- fused cell (uses gq0 = gates[t]) ----
        unsigned short hv[4];
        #pragma unroll
        for (int j = 0; j < 4; ++j) {
            float gi = acc[0][j] + b2f(gq0[j].x);
            float gf = acc[1][j] + b2f(gq0[j].y);
            float gg = acc[2][j] + b2f(gq0[j].z);
            float go = acc[3][j] + b2f(gq0[j].w);
            float c2 = sigm_f(gf) * cc[j] + sigm_f(gi) * tanh_f(gg);
            cc[j] = c2;
            hv[j] = f2b(sigm_f(go) * tanh_f(c2));
        }
        STORE_H(t + 1, hv)

        // 2-deep gates prefetch, AFTER the flag store
        if (t + 2 < T_) {
            #pragma unroll
            for (int j = 0; j < 4; ++j)
                gq2[j] = *(const ushort4*)(gates +
                    ((size_t)(t + 2) << 20) + gq_base + ((size_t)j << 12));
        }
        #pragma unroll
        for (int j = 0; j < 4; ++j) { gq0[j] = gq1[j]; gq1[j] = gq2[j]; }
    }
    #undef STORE_H
    #undef POLL_GROUP
}

// ---------------------------------------------------------------------------
// Fused prep (unchanged from round 16).
// ---------------------------------------------------------------------------
__global__ void fused_prep(
    const float* __restrict__ emb, const float* __restrict__ W_ih,
    const float* __restrict__ W_hh, const float* __restrict__ W_out,
    const float* __restrict__ X, const float* __restrict__ W_f,
    const int* __restrict__ labels,
    const float* __restrict__ b_ih, const float* __restrict__ b_hh,
    unsigned short* __restrict__ emb_bf, unsigned short* __restrict__ WihE_bf,
    unsigned short* __restrict__ WihA_bf, unsigned short* __restrict__ Whh_bf,
    unsigned short* __restrict__ Wout_bf,
    unsigned short* __restrict__ X_bf, unsigned short* __restrict__ Wf_bf,
    int* __restrict__ idxEmb, int* __restrict__ idxLog,
    float* __restrict__ bsum_perm)
{
    const int i = blockIdx.x * 256 + threadIdx.x;

    if (i < B_ * T_) {
        {
            int t = i >> 8, b = i & (B_ - 1);
            int tsrc = (t == 0) ? (T_ - 1) : (t - 1);
            idxEmb[i] = labels[b * T_ + tsrc];
        }
        {
            int b = i / T_, t = i % T_;
            idxLog[i] = (t + 1) * 16384 + b;
        }
    }
    if (i < G4_) {
        int w = ((i & 3) << 10) | (i >> 2);
        bsum_perm[i] = b_ih[w] + b_hh[w];
    }

    const float* src = nullptr;
    unsigned short* dst = nullptr;
    bool zero = false;
    if (i < 640128) {
        int r = i >> 7, c4 = i & 127;
        src = emb + (size_t)r * 512 + c4 * 4;
        dst = emb_bf + (size_t)r * 512 + c4 * 4;
    } else if (i < 1164416) {
        int j = i - 640128, r = j >> 7, c4 = j & 127;
        src = W_ih + (size_t)r * 1024 + 512 + c4 * 4;
        dst = WihE_bf + (size_t)r * 512 + c4 * 4;
    } else if (i < 1688704) {
        int j = i - 1164416, r = j >> 7, c4 = j & 127;
        src = W_ih + (size_t)r * 1024 + c4 * 4;
        dst = WihA_bf + (size_t)r * 512 + c4 * 4;
    } else if (i < 2737280) {
        int j = i - 1688704, r = j >> 8, c4 = j & 255;
        src = W_hh + (size_t)r * 1024 + c4 * 4;
        dst = Whh_bf + (size_t)r * 1024 + c4 * 4;
    } else if (i < 4048000) {
        int j = i - 2737280, r = j >> 8, c4 = j & 255;
        zero = (r >= V_);
        src = W_out + (size_t)r * 1024 + c4 * 4;
        dst = Wout_bf + (size_t)r * 1024 + c4 * 4;
    } else if (i < 4179072) {
        int j = i - 4048000, r = j >> 9, c4 = j & 511;
        src = X + (size_t)r * 2048 + c4 * 4;
        dst = X_bf + (size_t)r * 2048 + c4 * 4;
    } else if (i < 4441216) {
        int j = i - 4179072, r = j >> 9, c4 = j & 511;
        src = W_f + (size_t)r * 2048 + c4 * 4;
        dst = Wf_bf + (size_t)r * 2048 + c4 * 4;
    } else {
        return;
    }

    ushort4 o;
    if (!zero) {
        float4 v = *(const float4*)src;
        o.x = f2b(v.x); o.y = f2b(v.y); o.z = f2b(v.z); o.w = f2b(v.w);
    } else {
        o = make_ushort4(0, 0, 0, 0);
    }
    *(ushort4*)dst = o;
}

extern "C" void kernel_launch(void* const* d_in, const int* in_sizes, int n_in,
                              void* d_out, int out_size, void* d_ws, size_t ws_size,
                              hipStream_t stream)
{
    const float* X      = (const float*)d_in[0];
    const int*   labels = (const int*)  d_in[1];
    const float* W_f    = (const float*)d_in[2];
    const float* b_f    = (const float*)d_in[3];
    const float* emb    = (const float*)d_in[4];
    const float* W_ih   = (const float*)d_in[5];
    const float* W_hh   = (const float*)d_in[6];
    const float* b_ih   = (const float*)d_in[7];
    const float* b_hh   = (const float*)d_in[8];
    const float* W_out  = (const float*)d_in[9];
    const float* b_out  = (const float*)d_in[10];
    float* out = (float*)d_out;
    (void)in_sizes; (void)n_in; (void)out_size; (void)ws_size;

    char* ws = (char*)d_ws;
    size_t off = 0;
    auto alloc = [&](size_t bytes) {
        void* p = ws + off;
        off += (bytes + 255) & ~(size_t)255;
        return p;
    };
    unsigned short* emb_bf  = (unsigned short*)alloc((size_t)(V_ + 1) * E_ * 2);
    unsigned short* WihE_bf = (unsigned short*)alloc((size_t)G4_ * E_ * 2);
    unsigned short* WihA_bf = (unsigned short*)alloc((size_t)G4_ * E_ * 2);
    unsigned short* Whh_bf  = (unsigned short*)alloc((size_t)G4_ * H_ * 2);
    unsigned short* Wout_bf = (unsigned short*)alloc((size_t)5120 * H_ * 2);
    unsigned short* hs_bf   = (unsigned short*)alloc((size_t)(T_ + 1) * 262144 * 2);
    unsigned short* feat_bf = (unsigned short*)alloc((size_t)B_ * E_ * 2);
    float* bsum_perm = (float*)alloc(G4_ * 4);
    int*   idxEmb    = (int*)  alloc(B_ * T_ * 4);
    int*   idxLog    = (int*)  alloc(B_ * T_ * 4);
    unsigned int* flags = (unsigned int*)alloc((size_t)(T_ + 1) * 256 * 4);

    // d_out reuse: gates_bf at front (consumed before logits overwrites);
    // baseMat at 22M floats; X_bf / Wf_bf scratch at 25M / 26M.
    unsigned short* gates_bf = (unsigned short*)out;
    float* baseMat = out + 22 * 1024 * 1024;
    unsigned short* X_bf  = (unsigned short*)(out + 25 * 1024 * 1024);
    unsigned short* Wf_bf = (unsigned short*)(out + 26 * 1024 * 1024);

    hipMemsetAsync(flags, 0, (size_t)(T_ + 1) * 256 * 4, stream);

    fused_prep<<<(4441216 + 255) / 256, 256, 0, stream>>>(
        emb, W_ih, W_hh, W_out, X, W_f, labels, b_ih, b_hh,
        emb_bf, WihE_bf, WihA_bf, Whh_bf, Wout_bf, X_bf, Wf_bf,
        idxEmb, idxLog, bsum_perm);

    // features (bf16) = X_bf @ Wf_bf^T + b_f   [256,512] K=2048 (MFMA)
    gemm_mfma<2><<<dim3(E_ / 128, B_ / 128), 256, 0, stream>>>(
        X_bf, IN_, 0, nullptr, Wf_bf, IN_, 0, b_f,
        nullptr, 0, 0, feat_bf, E_, E_, IN_);

    // baseMat (permuted-linear f32) = feat @ WihA(q-mapped)^T + bsum_perm
    gemm_mfma<0><<<dim3(G4_ / 128, B_ / 128), 256, 0, stream>>>(
        feat_bf, E_, 0, nullptr, WihA_bf, E_, 1, nullptr,
        bsum_perm, 0, 0, baseMat, G4_, G4_, E_);

    // gates_bf[t,b,hc,q] = gather(emb_bf) @ WihE(q-mapped)^T + baseMat[b]
    gemm_mfma<1><<<dim3(G4_ / 128, (B_ * T_) / 128), 256, 0, stream>>>(
        emb_bf, E_, 0, idxEmb, WihE_bf, E_, 1, nullptr,
        baseMat, B_ - 1, G4_, gates_bf, G4_, G4_, E_);

    // ---- persistent recurrence (all 40 steps, one plain launch) ----
    {
        hipFuncSetAttribute((const void*)recur_persist,
                            hipFuncAttributeMaxDynamicSharedMemorySize, 131072);
        recur_persist<<<256, 256, 131072, stream>>>(hs_bf, Whh_bf, gates_bf, flags);
    }

    // logits = gather(hs_bf blocked) @ W_out^T + b_out   [10240,5000] K=1024
    gemm_big<<<dim3(5120 / 128, 10240 / 256), 256, 0, stream>>>(
        hs_bf, idxLog, Wout_bf, b_out, out);
}